// Round 6
// baseline (11876.882 us; speedup 1.0000x reference)
//
#include <hip/hip_runtime.h>

// spatialAttentionScaledGCN — MI355X single-dispatch dataflow version.
// B=8, N=512, T=12, F=32, O=64. All I/O fp32.
// R6: ALL stats/pred work (11 Jacobi steps + final) in ONE plain launch of
//     17024 independent 256-thr blocks. Each block atomically grabs a ticket;
//     tickets enumerate work items in TOPOLOGICAL dependency order:
//       [step i: 704 stats items][704 pred items] x 11, then 768 final-stats,
//       768 final-pred. A block holding ticket k knows all items <k are held
//       by started (hence resident-or-finished) blocks; deps are all <k, so
//       the smallest unfinished item can always run -> deadlock-free under
//       ANY dispatch order / partial residency (fixes R5's hang).
//     Deps via monotone per-unit counters (device-scope acq/rel):
//       stats(u,i): predCnt[u] >= 8i
//       pred(u,i):  statsCnt[u] >= 8(i+1); predCnt[u] >= 8i;
//                   predCnt[u-1] >= 8i (t>=2); predCnt[u+1] >= 8i (t<=10, WAR)
//       final stats(u): predCnt[u] >= 88 (t>=1)
//       final pred(u):  statsCnt[u] >= 96 (t>=1) / 8 (t==0)
//     Item bodies identical to R4's verified stats/pred kernels.

#define B_ 8
#define N_ 512
#define T_ 12
#define F_ 32
#define O_ 64

// item-space constants
#define SI_   704            // stats items per step  (88 units * 8 blocks)
#define STEPI 1408           // items per step
#define JT_   15488          // 11 * STEPI
#define FS1_  16256          // JT_ + 768 (final stats)
#define NMEGA 17024          // FS1_ + 768 (final pred)

typedef unsigned int uint_t;
typedef unsigned short ushort_t;
typedef _Float16 f16_t;
typedef _Float16 f16x4 __attribute__((ext_vector_type(4)));
typedef _Float16 f16x8 __attribute__((ext_vector_type(8)));
typedef float f32x4 __attribute__((ext_vector_type(4)));

__device__ __forceinline__ int xidx(int b, int n, int t, int f) {
    return ((b * N_ + n) * T_ + t) * F_ + f;
}
__device__ __forceinline__ f16x8 load_frag8(const float* p) {
    float4 a = *reinterpret_cast<const float4*>(p);
    float4 b = *reinterpret_cast<const float4*>(p + 4);
    f16x8 r;
    r[0] = (f16_t)a.x; r[1] = (f16_t)a.y; r[2] = (f16_t)a.z; r[3] = (f16_t)a.w;
    r[4] = (f16_t)b.x; r[5] = (f16_t)b.y; r[6] = (f16_t)b.z; r[7] = (f16_t)b.w;
    return r;
}
union U2H4 { uint2 u; f16x4 h; };

// ---------------------------------------------------------------------------
__global__ __launch_bounds__(256)
void permute_kernel(const float* __restrict__ src, ushort_t* __restrict__ dst)
{
    __shared__ float Lp[16][516];
    const int tid = threadIdx.x;
    const int mc  = blockIdx.x;               // 0..31 row-chunk
    const int s   = blockIdx.y;               // slice (b*12+t for phase; 0 for adj)
    src += (size_t)s * N_ * N_ + (size_t)mc * 16 * N_;
    uint_t* dstu = (uint_t*)dst + (size_t)s * 131072 + (size_t)mc * 4096;

    #pragma unroll
    for (int k = 0; k < 32; ++k) {
        int idx = tid + 256 * k;
        Lp[idx >> 9][idx & 511] = src[idx];
    }
    __syncthreads();
    #pragma unroll
    for (int k = 0; k < 16; ++k) {
        int u    = tid + 256 * k;
        int nt   = u >> 7;
        int r    = u & 127;
        int quad = r >> 5;
        int cl   = (r >> 1) & 15;
        int m0   = quad * 4 + (r & 1) * 2;
        int n    = nt * 16 + cl;
        union { f16_t h[2]; uint_t i; } pk;
        pk.h[0] = (f16_t)Lp[m0][n];
        pk.h[1] = (f16_t)Lp[m0 + 1][n];
        dstu[u] = pk.i;
    }
}

// ---------------------------------------------------------------------------
__device__ __forceinline__ void waitCnt(uint_t* p, uint_t v) {
    while (__hip_atomic_load(p, __ATOMIC_ACQUIRE, __HIP_MEMORY_SCOPE_AGENT) < v)
        __builtin_amdgcn_s_sleep(16);
}

// stats item: wave w owns m-tile (j*4+w); identical math to R4 stats_kernel.
__device__ __forceinline__ void do_stats(const float* __restrict__ xs,
                                         int b, int t, int j, float2* __restrict__ MSu)
{
    const int tid = threadIdx.x, w = tid >> 6, l = tid & 63;
    const int quad = l >> 4, col = l & 15;
    const int mb = (j * 4 + w) * 16;
    const float inv_f = 0.17677669529663687f;

    f16x8 bm = load_frag8(&xs[xidx(b, mb + col, t, quad * 8)]);
    float M = -1e30f, S = 0.f;
    #pragma unroll 4
    for (int nt2 = 0; nt2 < 32; ++nt2) {
        f16x8 an = load_frag8(&xs[xidx(b, nt2 * 16 + col, t, quad * 8)]);
        f32x4 s4 = __builtin_amdgcn_mfma_f32_16x16x32_f16(
                       an, bm, (f32x4){0.f, 0.f, 0.f, 0.f}, 0, 0, 0);
        float m4 = fmaxf(fmaxf(s4[0], s4[1]), fmaxf(s4[2], s4[3])) * inv_f;
        float Mn = fmaxf(M, m4);
        S = S * __expf(M - Mn)
          + (__expf(s4[0] * inv_f - Mn) + __expf(s4[1] * inv_f - Mn))
          + (__expf(s4[2] * inv_f - Mn) + __expf(s4[3] * inv_f - Mn));
        M = Mn;
    }
    #pragma unroll
    for (int d = 16; d < 64; d <<= 1) {
        float Mo = __shfl_xor(M, d, 64), So = __shfl_xor(S, d, 64);
        float Mn = fmaxf(M, Mo);
        S = S * __expf(M - Mn) + So * __expf(Mo - Mn);
        M = Mn;
    }
    if (l < 16)
        MSu[mb + l] = make_float2(M, inv_f / S);
}

// pred item: wave w owns n-tile (j*4+w); identical math to R4 pred_kernel.
__device__ __forceinline__ void do_pred(const float* __restrict__ xs,
                                        const float* __restrict__ xp, int tp,
                                        float* __restrict__ dst,
                                        const ushort_t* __restrict__ phase_h,
                                        const ushort_t* __restrict__ adj_h,
                                        const float* __restrict__ mask,
                                        const float2* __restrict__ MSu,
                                        int b, int t, int j, int u, bool fin)
{
    const int tid = threadIdx.x, w = tid >> 6, l = tid & 63;
    const int quad = l >> 4, col = l & 15;
    const int nt = j * 4 + w;
    const float inv_f = 0.17677669529663687f;

    f16x8 bf = load_frag8(&xs[xidx(b, nt * 16 + col, t, quad * 8)]);
    const uint_t* phu = (const uint_t*)phase_h + (size_t)u * 131072 + nt * 128 + l * 2;
    const uint_t* adu = (const uint_t*)adj_h + nt * 128 + l * 2;
    const float2* msp = MSu + quad * 4;

    f32x4 acc0 = (f32x4){0.f, 0.f, 0.f, 0.f};
    f32x4 acc1 = (f32x4){0.f, 0.f, 0.f, 0.f};

    #pragma unroll 2
    for (int c = 0; c < 32; ++c) {
        const int mb = c * 16;
        f16x8 af = load_frag8(&xs[xidx(b, mb + col, t, quad * 8)]);
        U2H4 ph; ph.u = *(const uint2*)(phu + (size_t)c * 4096);
        U2H4 aj;
        if (fin) aj.u = *(const uint2*)(adu + (size_t)c * 4096);
        float4 msA = *(const float4*)(msp + mb);
        float4 msB = *(const float4*)(msp + mb + 2);
        f16x4 bp0, bp1;
        #pragma unroll
        for (int jj = 0; jj < 4; ++jj) {
            bp0[jj] = (f16_t)xp[xidx(b, mb + quad * 4 + jj, tp, col)];
            bp1[jj] = (f16_t)xp[xidx(b, mb + quad * 4 + jj, tp, 16 + col)];
        }
        f32x4 s4 = __builtin_amdgcn_mfma_f32_16x16x32_f16(
                       af, bf, (f32x4){0.f, 0.f, 0.f, 0.f}, 0, 0, 0);
        const float Mv[4] = {msA.x, msA.z, msB.x, msB.z};
        const float Sv[4] = {msA.y, msA.w, msB.y, msB.w};
        f16x4 wf;
        #pragma unroll
        for (int v = 0; v < 4; ++v) {
            float e = __expf(s4[v] * inv_f - Mv[v]) * Sv[v] * (float)ph.h[v];
            if (fin) e *= (float)aj.h[v];
            wf[v] = (f16_t)e;
        }
        acc0 = __builtin_amdgcn_mfma_f32_16x16x16f16(wf, bp0, acc0, 0, 0, 0);
        acc1 = __builtin_amdgcn_mfma_f32_16x16x16f16(wf, bp1, acc1, 0, 0, 0);
    }

    #pragma unroll
    for (int v = 0; v < 4; ++v) {
        const int n = nt * 16 + quad * 4 + v;
        if (fin) {
            float* d0 = &dst[((size_t)u * N_ + n) * F_ + col];
            d0[0]  = acc0[v];
            d0[16] = acc1[v];
        } else {
            const int i0 = xidx(b, n, t, col);
            const float mk = mask[n];
            dst[i0]      = (mk != 0.f) ? xs[i0]      : acc0[v];
            dst[i0 + 16] = (mk != 0.f) ? xs[i0 + 16] : acc1[v];
        }
    }
}

// ---------------------------------------------------------------------------
// ctrl layout (uints): [0]=ticket; statsCnt[u]=ctrl[16+u*16]; predCnt[u]=ctrl[1600+u*16]
__global__ __launch_bounds__(256)
void mega_kernel(const float* __restrict__ x,
                 const float* __restrict__ mask,
                 float* __restrict__ xA, float* __restrict__ xB,
                 float* __restrict__ agg,
                 const ushort_t* __restrict__ phase_h,
                 const ushort_t* __restrict__ adj_h,
                 float2* __restrict__ MS,
                 uint_t* __restrict__ ctrl)
{
    __shared__ uint_t sT;
    const int tid = threadIdx.x;
    if (tid == 0)
        sT = __hip_atomic_fetch_add(ctrl, 1u, __ATOMIC_RELAXED, __HIP_MEMORY_SCOPE_AGENT);
    __syncthreads();
    const uint_t tk = sT;

    int typ, i, j, b, t;
    if (tk < JT_) {
        i = tk / STEPI;
        uint_t r = tk % STEPI;
        typ = (r < SI_) ? 0 : 1;
        uint_t r2 = (r < SI_) ? r : r - SI_;
        uint_t uu = r2 >> 3; j = r2 & 7;
        b = uu / 11; t = uu % 11 + 1;
    } else if (tk < FS1_) {
        typ = 2; uint_t r = tk - JT_;
        uint_t u0 = r >> 3; j = r & 7;
        b = u0 / T_; t = u0 % T_; i = 11;
    } else {
        typ = 3; uint_t r = tk - FS1_;
        uint_t u0 = r >> 3; j = r & 7;
        b = u0 / T_; t = u0 % T_; i = 11;
    }
    const int u = b * T_ + t;
    uint_t* statsCnt = ctrl + 16 + u * 16;
    uint_t* predCnt  = ctrl + 1600 + u * 16;

    // ---- dependency waits (all deps have strictly smaller tickets) ----
    if (tid == 0) {
        if (typ == 0) {
            if (i > 0) waitCnt(predCnt, 8u * i);
        } else if (typ == 1) {
            waitCnt(statsCnt, 8u * (i + 1));
            if (i > 0) {
                waitCnt(predCnt, 8u * i);
                if (t >= 2)  waitCnt(ctrl + 1600 + (u - 1) * 16, 8u * i);
                if (t <= 10) waitCnt(ctrl + 1600 + (u + 1) * 16, 8u * i);  // WAR
            }
        } else if (typ == 2) {
            if (t >= 1) waitCnt(predCnt, 88u);
        } else {
            waitCnt(statsCnt, (t >= 1) ? 96u : 8u);
        }
    }
    __syncthreads();
    __threadfence();                         // acquire: drop stale cached lines

    // ---- work ----
    float* bufs[2] = { xA, xB };
    if (typ == 0) {
        const float* cur = (i == 0) ? x : bufs[(i - 1) & 1];
        do_stats(cur, b, t, j, MS + (size_t)u * N_);
    } else if (typ == 1) {
        const float* cur = (i == 0) ? x : bufs[(i - 1) & 1];
        const float* xp  = (t == 1) ? x : cur;
        do_pred(cur, xp, t - 1, bufs[i & 1], phase_h, adj_h, mask,
                MS + (size_t)u * N_, b, t, j, u, false);
    } else if (typ == 2) {
        const float* xf = (t == 0) ? x : bufs[0];
        do_stats(xf, b, t, j, MS + (size_t)u * N_);
    } else {
        const float* xf = (t == 0) ? x : bufs[0];
        do_pred(xf, xf, t, agg, phase_h, adj_h, mask,
                MS + (size_t)u * N_, b, t, j, u, true);
    }

    // ---- completion publish ----
    __threadfence();                         // release own stores device-wide
    __syncthreads();
    if (tid == 0) {
        if (typ == 0 || typ == 2)
            __hip_atomic_fetch_add(statsCnt, 1u, __ATOMIC_RELEASE, __HIP_MEMORY_SCOPE_AGENT);
        else if (typ == 1)
            __hip_atomic_fetch_add(predCnt, 1u, __ATOMIC_RELEASE, __HIP_MEMORY_SCOPE_AGENT);
        // typ 3: agg consumed by the separately-dispatched proj kernel
    }
}

// out[b,n,t,o] = relu(sum_f agg[b,t,n,f] * theta[f,o])
__global__ __launch_bounds__(256)
void proj_kernel(const float* __restrict__ agg, const float* __restrict__ theta,
                 float* __restrict__ out)
{
    __shared__ float th[F_ * O_];
    int tid = threadIdx.x;
    #pragma unroll
    for (int p = 0; p < 8; ++p) th[tid + 256 * p] = theta[tid + 256 * p];
    __syncthreads();
    int g  = blockIdx.x * 256 + tid;           // ((b*N+n)*T+t)*O+o
    int o  = g & 63;
    int r  = g >> 6;
    int tt = r % T_;
    int r2 = r / T_;
    int n  = r2 & 511;
    int b  = r2 >> 9;
    const float* a = &agg[((b * T_ + tt) * N_ + n) * F_];
    float s = 0.f;
    #pragma unroll
    for (int f = 0; f < F_; ++f) s += a[f] * th[f * O_ + o];
    out[g] = fmaxf(s, 0.f);
}

extern "C" void kernel_launch(void* const* d_in, const int* in_sizes, int n_in,
                              void* d_out, int out_size, void* d_ws, size_t ws_size,
                              hipStream_t stream)
{
    const float* x     = (const float*)d_in[0];
    const float* phase = (const float*)d_in[1];
    const float* adj   = (const float*)d_in[2];
    const float* mask  = (const float*)d_in[3];
    const float* theta = (const float*)d_in[4];
    float* out = (float*)d_out;

    const size_t XE = (size_t)B_ * N_ * T_ * F_;            // 1,572,864 floats
    float*    xA      = (float*)d_ws;                       //  6.3 MB
    float*    xB      = xA + XE;                            //  6.3 MB
    float*    agg     = xB + XE;                            //  6.3 MB
    ushort_t* phase_h = (ushort_t*)(agg + XE);              // 50.3 MB
    ushort_t* adj_h   = phase_h + (size_t)96 * N_ * N_;     // 0.5 MB
    float2*   MS      = (float2*)(adj_h + (size_t)N_ * N_); // 0.4 MB
    uint_t*   ctrl    = (uint_t*)(MS + (size_t)96 * N_);    // 12.8 KB control

    hipMemsetAsync(ctrl, 0, 12800, stream);
    permute_kernel<<<dim3(32, 96), 256, 0, stream>>>(phase, phase_h);
    permute_kernel<<<dim3(32, 1), 256, 0, stream>>>(adj, adj_h);

    mega_kernel<<<dim3(NMEGA), dim3(256), 0, stream>>>(
        x, mask, xA, xB, agg, phase_h, adj_h, MS, ctrl);

    proj_kernel<<<(B_ * N_ * T_ * O_) / 256, 256, 0, stream>>>(agg, theta, out);
}

// Round 7
// 1007.410 us; speedup vs baseline: 11.7895x; 11.7895x over previous
//
#include <hip/hip_runtime.h>

// spatialAttentionScaledGCN — MI355X MFMA version.
// B=8, N=512, T=12, F=32, O=64. All I/O fp32.
// R7: R4's dispatch graph (2 permute + 11x(stats,pred) + final + proj; no
//     atomics, no cross-block sync — R5/R6 proved fabric sync is ms-scale).
//     New: phase permuted so each lane reads ONE dwordx4 covering TWO chunks
//     (chunk-pair interleave), pred loops 16 chunk-pairs with unroll 2 (4
//     chunks of loads in flight), __launch_bounds__(256,3) lifts the VGPR cap
//     (R4 was squeezed to 64 -> ~0.8 TB/s effective on the 45 MB/pass phase
//     stream). stats: 4 independent online-softmax streams (ILP on the
//     serial max/exp chain).

#define B_ 8
#define N_ 512
#define T_ 12
#define F_ 32
#define O_ 64

typedef unsigned int uint_t;
typedef unsigned short ushort_t;
typedef _Float16 f16_t;
typedef _Float16 f16x4 __attribute__((ext_vector_type(4)));
typedef _Float16 f16x8 __attribute__((ext_vector_type(8)));
typedef float f32x4 __attribute__((ext_vector_type(4)));

__device__ __forceinline__ int xidx(int b, int n, int t, int f) {
    return ((b * N_ + n) * T_ + t) * F_ + f;
}
__device__ __forceinline__ f16x8 load_frag8(const float* p) {
    float4 a = *reinterpret_cast<const float4*>(p);
    float4 b = *reinterpret_cast<const float4*>(p + 4);
    f16x8 r;
    r[0] = (f16_t)a.x; r[1] = (f16_t)a.y; r[2] = (f16_t)a.z; r[3] = (f16_t)a.w;
    r[4] = (f16_t)b.x; r[5] = (f16_t)b.y; r[6] = (f16_t)b.z; r[7] = (f16_t)b.w;
    return r;
}
union U2H4 { uint2 u; f16x4 h; };

// ---------------------------------------------------------------------------
// Permute one 512x512 fp32 slice into chunk-pair-interleaved MFMA f16 layout.
// Block handles chunk-pair cp (32 rows). uint4 index per slice:
//   cp*2048 + nt*64 + l   (l = quad*16 + col)
//   .x=(rows 2cp*16+quad*4 +0,+1) .y=(+2,+3)  [chunk 2cp]
//   .z/.w same rows of chunk 2cp+1, all at column n = nt*16+col.
// Consumer lane l reads its 8 halves for BOTH chunks with one dwordx4.
__global__ __launch_bounds__(256)
void permute_kernel(const float* __restrict__ src, ushort_t* __restrict__ dst)
{
    __shared__ float Lp[32][516];             // 66 KB
    const int tid = threadIdx.x;
    const int cp  = blockIdx.x;               // 0..15 chunk-pair (32 rows)
    const int s   = blockIdx.y;               // slice (b*12+t for phase; 0 adj)
    src += (size_t)s * N_ * N_ + (size_t)cp * 32 * N_;
    uint4* dstu = (uint4*)dst + (size_t)s * 32768 + (size_t)cp * 2048;

    #pragma unroll
    for (int k = 0; k < 64; ++k) {
        int idx = tid + 256 * k;              // 0..16383
        Lp[idx >> 9][idx & 511] = src[idx];
    }
    __syncthreads();
    #pragma unroll
    for (int k = 0; k < 8; ++k) {
        int u    = tid + 256 * k;             // 0..2047
        int nt   = u >> 6;
        int l    = u & 63;
        int quad = l >> 4;
        int cl   = l & 15;
        int n    = nt * 16 + cl;
        int r0   = quad * 4;
        union { f16_t h[2]; uint_t i; } p0, p1, p2, p3;
        p0.h[0] = (f16_t)Lp[r0][n];      p0.h[1] = (f16_t)Lp[r0 + 1][n];
        p1.h[0] = (f16_t)Lp[r0 + 2][n];  p1.h[1] = (f16_t)Lp[r0 + 3][n];
        p2.h[0] = (f16_t)Lp[16 + r0][n];     p2.h[1] = (f16_t)Lp[16 + r0 + 1][n];
        p3.h[0] = (f16_t)Lp[16 + r0 + 2][n]; p3.h[1] = (f16_t)Lp[16 + r0 + 3][n];
        dstu[u] = make_uint4(p0.i, p1.i, p2.i, p3.i);
    }
}

// ---------------------------------------------------------------------------
// Softmax row stats. Block = 256 thr = 4 waves, no LDS. Wave owns m-tile
// blockIdx.x*4+w; transposed score MFMA puts m on C-cols; 4 independent
// online (M,S) streams over nt%4 break the serial chain; merge + 2-stage
// cross-quad shuffle. MS[m] = (M, inv_f/S).
template <int FINAL>
__global__ __launch_bounds__(256, 4)
void stats_kernel(const float* __restrict__ x0,
                  const float* __restrict__ xcur,
                  float2* __restrict__ MS)
{
    const int tid  = threadIdx.x;
    const int w    = tid >> 6;
    const int l    = tid & 63;
    const int quad = l >> 4;
    const int col  = l & 15;
    const int t    = FINAL ? blockIdx.y : blockIdx.y + 1;
    const int b    = blockIdx.z;
    const int mb   = (blockIdx.x * 4 + w) * 16;
    const float inv_f = 0.17677669529663687f;
    const float* xs = (FINAL && t == 0) ? x0 : xcur;

    f16x8 bm = load_frag8(&xs[xidx(b, mb + col, t, quad * 8)]);

    float M[4] = {-1e30f, -1e30f, -1e30f, -1e30f};
    float S[4] = {0.f, 0.f, 0.f, 0.f};
    #pragma unroll 2
    for (int base = 0; base < 8; ++base) {
        #pragma unroll
        for (int ss = 0; ss < 4; ++ss) {
            const int nt2 = base * 4 + ss;
            f16x8 an = load_frag8(&xs[xidx(b, nt2 * 16 + col, t, quad * 8)]);
            f32x4 s4 = __builtin_amdgcn_mfma_f32_16x16x32_f16(
                           an, bm, (f32x4){0.f, 0.f, 0.f, 0.f}, 0, 0, 0);
            float m4 = fmaxf(fmaxf(s4[0], s4[1]), fmaxf(s4[2], s4[3])) * inv_f;
            float Mn = fmaxf(M[ss], m4);
            S[ss] = S[ss] * __expf(M[ss] - Mn)
                  + (__expf(s4[0] * inv_f - Mn) + __expf(s4[1] * inv_f - Mn))
                  + (__expf(s4[2] * inv_f - Mn) + __expf(s4[3] * inv_f - Mn));
            M[ss] = Mn;
        }
    }
    // merge 4 streams
    float M01 = fmaxf(M[0], M[1]);
    float S01 = S[0] * __expf(M[0] - M01) + S[1] * __expf(M[1] - M01);
    float M23 = fmaxf(M[2], M[3]);
    float S23 = S[2] * __expf(M[2] - M23) + S[3] * __expf(M[3] - M23);
    float Mm  = fmaxf(M01, M23);
    float Sm  = S01 * __expf(M01 - Mm) + S23 * __expf(M23 - Mm);
    // cross-quad reduce (lanes 16 & 32 apart share the same m = mb+col)
    #pragma unroll
    for (int d = 16; d < 64; d <<= 1) {
        float Mo = __shfl_xor(Mm, d, 64), So = __shfl_xor(Sm, d, 64);
        float Mn = fmaxf(Mm, Mo);
        Sm = Sm * __expf(Mm - Mn) + So * __expf(Mo - Mn);
        Mm = Mn;
    }
    if (l < 16)
        MS[(size_t)(b * T_ + t) * N_ + mb + l] = make_float2(Mm, inv_f / Sm);
}

// ---------------------------------------------------------------------------
// Pred/agg kernel. Block = 256 thr = 4 waves, no LDS/barriers/shuffles.
// Wave owns n-tile nt = blockIdx.x*4+w, loops 16 chunk-PAIRS; phase (and adj)
// fetched as one dwordx4 per lane per pair. FINAL=1: *adj, Xp=X_t, store agg.
template <int FINAL>
__global__ __launch_bounds__(256, 3)
void pred_kernel(const float* __restrict__ x0,
                 const float* __restrict__ xcur,
                 float* __restrict__ dst,            // xnext or agg
                 const ushort_t* __restrict__ phase_h,
                 const ushort_t* __restrict__ adj_h,
                 const float* __restrict__ mask,
                 const float2* __restrict__ MS)
{
    const int tid  = threadIdx.x;
    const int w    = tid >> 6;
    const int l    = tid & 63;
    const int quad = l >> 4;
    const int col  = l & 15;
    const int t    = FINAL ? blockIdx.y : blockIdx.y + 1;
    const int b    = blockIdx.z;
    const int nt   = blockIdx.x * 4 + w;             // wave's n-tile
    const float inv_f = 0.17677669529663687f;

    const float* xs     = (FINAL && t == 0) ? x0 : xcur;       // X_t source
    const float* xp_src = FINAL ? xs : ((t == 1) ? x0 : xcur); // pred operand
    const int    tp     = FINAL ? t : t - 1;

    f16x8 bf = load_frag8(&xs[xidx(b, nt * 16 + col, t, quad * 8)]);
    const uint4* phu4 = (const uint4*)phase_h + (size_t)(b * T_ + t) * 32768
                        + nt * 64 + l;
    const uint4* adu4 = (const uint4*)adj_h + nt * 64 + l;
    const float2* msp = MS + (size_t)(b * T_ + t) * N_ + quad * 4;

    f32x4 acc0 = (f32x4){0.f, 0.f, 0.f, 0.f};
    f32x4 acc1 = (f32x4){0.f, 0.f, 0.f, 0.f};

    #pragma unroll 2
    for (int cp = 0; cp < 16; ++cp) {
        const int mb0 = cp * 32;
        const int mb1 = mb0 + 16;
        // ---- issue all loads for both chunks up front ----
        uint4 phq = phu4[cp * 2048];
        uint4 ajq;
        if (FINAL) ajq = adu4[cp * 2048];
        f16x8 af0 = load_frag8(&xs[xidx(b, mb0 + col, t, quad * 8)]);
        f16x8 af1 = load_frag8(&xs[xidx(b, mb1 + col, t, quad * 8)]);
        float4 msA0 = *(const float4*)(msp + mb0);
        float4 msB0 = *(const float4*)(msp + mb0 + 2);
        float4 msA1 = *(const float4*)(msp + mb1);
        float4 msB1 = *(const float4*)(msp + mb1 + 2);
        f16x4 bp00, bp01, bp10, bp11;
        #pragma unroll
        for (int jj = 0; jj < 4; ++jj) {
            bp00[jj] = (f16_t)xp_src[xidx(b, mb0 + quad * 4 + jj, tp, col)];
            bp01[jj] = (f16_t)xp_src[xidx(b, mb0 + quad * 4 + jj, tp, 16 + col)];
            bp10[jj] = (f16_t)xp_src[xidx(b, mb1 + quad * 4 + jj, tp, col)];
            bp11[jj] = (f16_t)xp_src[xidx(b, mb1 + quad * 4 + jj, tp, 16 + col)];
        }

        f32x4 s40 = __builtin_amdgcn_mfma_f32_16x16x32_f16(
                        af0, bf, (f32x4){0.f, 0.f, 0.f, 0.f}, 0, 0, 0);
        f32x4 s41 = __builtin_amdgcn_mfma_f32_16x16x32_f16(
                        af1, bf, (f32x4){0.f, 0.f, 0.f, 0.f}, 0, 0, 0);

        U2H4 p0; p0.u = make_uint2(phq.x, phq.y);   // chunk 2cp
        U2H4 p1; p1.u = make_uint2(phq.z, phq.w);   // chunk 2cp+1
        U2H4 a0, a1;
        if (FINAL) { a0.u = make_uint2(ajq.x, ajq.y); a1.u = make_uint2(ajq.z, ajq.w); }

        const float Mv0[4] = {msA0.x, msA0.z, msB0.x, msB0.z};
        const float Sv0[4] = {msA0.y, msA0.w, msB0.y, msB0.w};
        const float Mv1[4] = {msA1.x, msA1.z, msB1.x, msB1.z};
        const float Sv1[4] = {msA1.y, msA1.w, msB1.y, msB1.w};

        f16x4 wf0, wf1;
        #pragma unroll
        for (int v = 0; v < 4; ++v) {
            float e0 = __expf(s40[v] * inv_f - Mv0[v]) * Sv0[v] * (float)p0.h[v];
            float e1 = __expf(s41[v] * inv_f - Mv1[v]) * Sv1[v] * (float)p1.h[v];
            if (FINAL) { e0 *= (float)a0.h[v]; e1 *= (float)a1.h[v]; }
            wf0[v] = (f16_t)e0;
            wf1[v] = (f16_t)e1;
        }
        acc0 = __builtin_amdgcn_mfma_f32_16x16x16f16(wf0, bp00, acc0, 0, 0, 0);
        acc1 = __builtin_amdgcn_mfma_f32_16x16x16f16(wf0, bp01, acc1, 0, 0, 0);
        acc0 = __builtin_amdgcn_mfma_f32_16x16x16f16(wf1, bp10, acc0, 0, 0, 0);
        acc1 = __builtin_amdgcn_mfma_f32_16x16x16f16(wf1, bp11, acc1, 0, 0, 0);
    }

    // ---- epilogue: exactly-once plain stores ----
    #pragma unroll
    for (int v = 0; v < 4; ++v) {
        const int n = nt * 16 + quad * 4 + v;
        if (FINAL) {
            float* d0 = &dst[((size_t)(b * T_ + t) * N_ + n) * F_ + col];
            d0[0]  = acc0[v];
            d0[16] = acc1[v];
        } else {
            const int i0 = xidx(b, n, t, col);
            const float mk = mask[n];
            dst[i0]      = (mk != 0.f) ? xcur[i0]      : acc0[v];
            dst[i0 + 16] = (mk != 0.f) ? xcur[i0 + 16] : acc1[v];
        }
    }
}

// out[b,n,t,o] = relu(sum_f agg[b,t,n,f] * theta[f,o])
__global__ __launch_bounds__(256)
void proj_kernel(const float* __restrict__ agg, const float* __restrict__ theta,
                 float* __restrict__ out)
{
    __shared__ float th[F_ * O_];
    int tid = threadIdx.x;
    #pragma unroll
    for (int p = 0; p < 8; ++p) th[tid + 256 * p] = theta[tid + 256 * p];
    __syncthreads();
    int g  = blockIdx.x * 256 + tid;           // ((b*N+n)*T+t)*O+o
    int o  = g & 63;
    int r  = g >> 6;
    int tt = r % T_;
    int r2 = r / T_;
    int n  = r2 & 511;
    int b  = r2 >> 9;
    const float* a = &agg[((b * T_ + tt) * N_ + n) * F_];
    float s = 0.f;
    #pragma unroll
    for (int f = 0; f < F_; ++f) s += a[f] * th[f * O_ + o];
    out[g] = fmaxf(s, 0.f);
}

extern "C" void kernel_launch(void* const* d_in, const int* in_sizes, int n_in,
                              void* d_out, int out_size, void* d_ws, size_t ws_size,
                              hipStream_t stream)
{
    const float* x     = (const float*)d_in[0];
    const float* phase = (const float*)d_in[1];
    const float* adj   = (const float*)d_in[2];
    const float* mask  = (const float*)d_in[3];
    const float* theta = (const float*)d_in[4];
    float* out = (float*)d_out;

    const size_t XE = (size_t)B_ * N_ * T_ * F_;            // 1,572,864 floats
    float*    xA      = (float*)d_ws;                       //  6.3 MB
    float*    xB      = xA + XE;                            //  6.3 MB
    float*    agg     = xB + XE;                            //  6.3 MB
    ushort_t* phase_h = (ushort_t*)(agg + XE);              // 50.3 MB
    ushort_t* adj_h   = phase_h + (size_t)96 * N_ * N_;     // 0.5 MB
    float2*   MS      = (float2*)(adj_h + (size_t)N_ * N_); // 0.4 MB

    permute_kernel<<<dim3(16, 96), 256, 0, stream>>>(phase, phase_h);
    permute_kernel<<<dim3(16, 1), 256, 0, stream>>>(adj, adj_h);

    const float* cur = x;
    float* bufs[2] = { xA, xB };
    for (int i = 0; i < T_ - 1; ++i) {                 // 11 Jacobi iterations
        float* nxt = bufs[i & 1];
        stats_kernel<0><<<dim3(8, T_ - 1, B_), 256, 0, stream>>>(x, cur, MS);
        pred_kernel<0><<<dim3(8, T_ - 1, B_), 256, 0, stream>>>(
            x, cur, nxt, phase_h, adj_h, mask, MS);
        cur = nxt;
    }
    stats_kernel<1><<<dim3(8, T_, B_), 256, 0, stream>>>(x, cur, MS);
    pred_kernel<1><<<dim3(8, T_, B_), 256, 0, stream>>>(
        x, cur, agg, phase_h, adj_h, mask, MS);
    proj_kernel<<<(B_ * N_ * T_ * O_) / 256, 256, 0, stream>>>(agg, theta, out);
}